// Round 3
// baseline (301.185 us; speedup 1.0000x reference)
//
#include <hip/hip_runtime.h>
#include <hip/hip_bf16.h>
#include <math.h>

// ParallelMLayer: x_seq, v_seq = scan over A=sigmoid(F@WA.T+bA),
// dt=softplus(F@Wdt.T+bdt)*0.1*1.5^(d/128), B=(F@WB.T+bB)*dt
// v_t = A_t v_{t-1} + B_t ; x_t = x_{t-1} + dt_t * v_t
//
// Pipeline: cvt(force,W -> bf16) -> fused bf16 MFMA GEMM (N=3072) with
// activation epilogue (A->ws, pre->d_out[v region], dt->d_out[x region])
// -> 3-pass chunked scan that finalizes v_seq/x_seq in-place in d_out.
// Workspace requirement: ~110 MB.

#define BDIM 4
#define LSEQ 4096
#define DDIM 1024
#define MROWS (BDIM*LSEQ)   // 16384
#define NCH 64              // scan chunks per sequence
#define CLEN (LSEQ/NCH)     // 64
#define LDA 40              // padded LDS stride (elems) to break bank conflicts

typedef __attribute__((ext_vector_type(8))) unsigned short u16x8;
typedef __attribute__((ext_vector_type(8))) short s16x8;
typedef __attribute__((ext_vector_type(4))) float f32x4;

__device__ inline ushort f2bf(float f) {
    unsigned u = __builtin_bit_cast(unsigned, f);
    unsigned r = (u + 0x7fffu + ((u >> 16) & 1u)) >> 16;
    return (ushort)r;
}

// ---- f32 -> bf16 conversion, 4 elems/thread ----
__global__ void cvt4(const float* __restrict__ src, ushort* __restrict__ dst, int n4) {
    int i = blockIdx.x * 256 + threadIdx.x;
    if (i >= n4) return;
    float4 v = reinterpret_cast<const float4*>(src)[i];
    ushort4 o;
    o.x = f2bf(v.x); o.y = f2bf(v.y); o.z = f2bf(v.z); o.w = f2bf(v.w);
    reinterpret_cast<ushort4*>(dst)[i] = o;
}

// ---- fused GEMM: C[i][j] = sum_k F[i][k] * Wcat[j][k], 128x128 tile, BK=32 ----
__global__ __launch_bounds__(256, 2) void gemm_fused(
    const ushort* __restrict__ F, const ushort* __restrict__ Wc,
    const float* __restrict__ biasA, const float* __restrict__ biasB,
    const float* __restrict__ biasDt,
    float* __restrict__ outA, float* __restrict__ outPre, float* __restrict__ outDt)
{
    __shared__ ushort As[128 * LDA];
    __shared__ ushort Bs[128 * LDA];
    const int t = threadIdx.x;
    const int bi = blockIdx.x;   // 0..127 M tiles
    const int bj = blockIdx.y;   // 0..23  N tiles
    const int lane = t & 63, wid = t >> 6;
    const int wm = wid >> 1, wn = wid & 1;   // 2x2 waves, each 64x64 out
    const int lr = lane & 15, lg = lane >> 4;
    const int sr = t >> 2;          // staging row 0..63
    const int sc = (t & 3) * 8;     // staging k-offset 0,8,16,24

    const size_t aBase = (size_t)bi * 128;
    const size_t bBase = (size_t)bj * 128;
    const ushort* ga0 = F + (aBase + sr) * DDIM + sc;
    const ushort* ga1 = F + (aBase + 64 + sr) * DDIM + sc;
    const ushort* gb0 = Wc + (bBase + sr) * DDIM + sc;
    const ushort* gb1 = Wc + (bBase + 64 + sr) * DDIM + sc;
    ushort* la0 = &As[sr * LDA + sc];
    ushort* la1 = &As[(64 + sr) * LDA + sc];
    ushort* lb0 = &Bs[sr * LDA + sc];
    ushort* lb1 = &Bs[(64 + sr) * LDA + sc];

    f32x4 acc[4][4] = {};

    for (int k0 = 0; k0 < DDIM; k0 += 32) {
        u16x8 ra0 = *reinterpret_cast<const u16x8*>(ga0 + k0);
        u16x8 ra1 = *reinterpret_cast<const u16x8*>(ga1 + k0);
        u16x8 rb0 = *reinterpret_cast<const u16x8*>(gb0 + k0);
        u16x8 rb1 = *reinterpret_cast<const u16x8*>(gb1 + k0);
        __syncthreads();   // previous iter's ds_reads done before overwrite
        *reinterpret_cast<u16x8*>(la0) = ra0;
        *reinterpret_cast<u16x8*>(la1) = ra1;
        *reinterpret_cast<u16x8*>(lb0) = rb0;
        *reinterpret_cast<u16x8*>(lb1) = rb1;
        __syncthreads();
        s16x8 af[4], bf[4];
#pragma unroll
        for (int m = 0; m < 4; m++)
            af[m] = *reinterpret_cast<const s16x8*>(&As[(wm * 64 + m * 16 + lr) * LDA + lg * 8]);
#pragma unroll
        for (int n = 0; n < 4; n++)
            bf[n] = *reinterpret_cast<const s16x8*>(&Bs[(wn * 64 + n * 16 + lr) * LDA + lg * 8]);
#pragma unroll
        for (int m = 0; m < 4; m++)
#pragma unroll
            for (int n = 0; n < 4; n++)
                acc[m][n] = __builtin_amdgcn_mfma_f32_16x16x32_bf16(af[m], bf[n], acc[m][n], 0, 0, 0);
    }

    // epilogue: C/D layout col=lane&15, row=(lane>>4)*4+reg
    const int mat = bj >> 3;                     // 0:A 1:B-pre 2:dt
    const int colBase = (bj & 7) * 128 + wn * 64;
    const size_t rowBase = (size_t)bi * 128 + wm * 64;

    if (mat == 0) {
#pragma unroll
        for (int n = 0; n < 4; n++) {
            const int d = colBase + n * 16 + lr;
            const float bb = biasA[d];
#pragma unroll
            for (int m = 0; m < 4; m++)
#pragma unroll
                for (int r = 0; r < 4; r++) {
                    const size_t row = rowBase + m * 16 + lg * 4 + r;
                    float s = acc[m][n][r] + bb;
                    outA[row * DDIM + d] = 1.0f / (1.0f + expf(-s));
                }
        }
    } else if (mat == 1) {
#pragma unroll
        for (int n = 0; n < 4; n++) {
            const int d = colBase + n * 16 + lr;
            const float bb = biasB[d];
#pragma unroll
            for (int m = 0; m < 4; m++)
#pragma unroll
                for (int r = 0; r < 4; r++) {
                    const size_t row = rowBase + m * 16 + lg * 4 + r;
                    outPre[row * DDIM + d] = acc[m][n][r] + bb;
                }
        }
    } else {
#pragma unroll
        for (int n = 0; n < 4; n++) {
            const int d = colBase + n * 16 + lr;
            const float bb = biasDt[d];
            const float scl = 0.1f * exp2f(0.58496250072f * (float)(d >> 7)); // 0.1*1.5^(d/128)
#pragma unroll
            for (int m = 0; m < 4; m++)
#pragma unroll
                for (int r = 0; r < 4; r++) {
                    const size_t row = rowBase + m * 16 + lg * 4 + r;
                    float s = acc[m][n][r] + bb;
                    float sp = fmaxf(s, 0.0f) + log1pf(expf(-fabsf(s)));
                    outDt[row * DDIM + d] = sp * scl;
                }
        }
    }
}

// ---- scan pass 1: per (b, chunk, d) composite map (a, c, bv, bx) ----
__global__ void scan_pass1(const float* __restrict__ A, const float* __restrict__ PRE,
                           const float* __restrict__ DT, float4* __restrict__ summ)
{
    const int dg = blockIdx.x & 3;
    const int c = (blockIdx.x >> 2) & (NCH - 1);
    const int b = blockIdx.x >> 8;
    const int d = dg * 256 + threadIdx.x;
    size_t idx = ((size_t)b * LSEQ + (size_t)c * CLEN) * DDIM + d;
    float a = 1.0f, cc = 0.0f, bv = 0.0f, bx = 0.0f;
    for (int i = 0; i < CLEN; i++) {
        float Av = A[idx], pv = PRE[idx], dtv = DT[idx];
        a *= Av;
        cc = fmaf(dtv, a, cc);
        bv = fmaf(Av, bv, pv * dtv);
        bx = fmaf(dtv, bv, bx);
        idx += DDIM;
    }
    summ[((size_t)b * NCH + c) * DDIM + d] = make_float4(a, cc, bv, bx);
}

// ---- scan pass 2: serial over chunks per channel -> carry-in (v, x) ----
__global__ void scan_pass2(const float4* __restrict__ summ, float2* __restrict__ carry)
{
    const int idx = blockIdx.x * 256 + threadIdx.x;   // 4096 channels
    const int b = idx >> 10, d = idx & 1023;
    float v = 0.0f, x = 0.0f;
    for (int c = 0; c < NCH; c++) {
        const size_t o = ((size_t)b * NCH + c) * DDIM + d;
        carry[o] = make_float2(v, x);
        float4 s = summ[o];
        x = x + s.y * v + s.w;   // x' = x + c*v + bx (uses OLD v)
        v = s.x * v + s.z;       // v' = a*v + bv
    }
}

// ---- scan pass 3: finalize with carry; in-place pre->v_seq, dt->x_seq ----
__global__ void scan_pass3(const float* __restrict__ A, float* __restrict__ PREV,
                           float* __restrict__ DTX, const float2* __restrict__ carry)
{
    const int dg = blockIdx.x & 3;
    const int c = (blockIdx.x >> 2) & (NCH - 1);
    const int b = blockIdx.x >> 8;
    const int d = dg * 256 + threadIdx.x;
    size_t idx = ((size_t)b * LSEQ + (size_t)c * CLEN) * DDIM + d;
    float2 cr = carry[((size_t)b * NCH + c) * DDIM + d];
    float v = cr.x, x = cr.y;
    for (int i = 0; i < CLEN; i++) {
        float Av = A[idx], pv = PREV[idx], dtv = DTX[idx];
        v = fmaf(Av, v, pv * dtv);
        x = fmaf(dtv, v, x);
        PREV[idx] = v;
        DTX[idx] = x;
        idx += DDIM;
    }
}

extern "C" void kernel_launch(void* const* d_in, const int* in_sizes, int n_in,
                              void* d_out, int out_size, void* d_ws, size_t ws_size,
                              hipStream_t stream) {
    const float* force = (const float*)d_in[2];
    const float* WA  = (const float*)d_in[5];
    const float* bA  = (const float*)d_in[6];
    const float* WB  = (const float*)d_in[7];
    const float* bB  = (const float*)d_in[8];
    const float* Wdt = (const float*)d_in[9];
    const float* bdt = (const float*)d_in[10];

    float* xseq = (float*)d_out;                          // [B,L,D] first output
    float* vseq = xseq + (size_t)MROWS * DDIM;            // [B,L,D] second output

    char* ws = (char*)d_ws;
    float*  wsA   = (float*) ws;                             // 64 MB: A gates
    ushort* Fb    = (ushort*)(ws + ((size_t)64  << 20));     // 32 MB: bf16 force
    ushort* Wcat  = (ushort*)(ws + ((size_t)96  << 20));     //  6 MB: bf16 [WA;WB;Wdt]
    float4* summ  = (float4*)(ws + ((size_t)104 << 20));     //  4 MB: chunk summaries
    float2* carry = (float2*)(ws + ((size_t)108 << 20));     //  2 MB: chunk carries

    const int n4_force = MROWS * DDIM / 4;     // 4194304
    const int n4_w = DDIM * DDIM / 4;          // 262144

    cvt4<<<n4_force / 256, 256, 0, stream>>>(force, Fb, n4_force);
    cvt4<<<n4_w / 256, 256, 0, stream>>>(WA,  Wcat,                 n4_w);
    cvt4<<<n4_w / 256, 256, 0, stream>>>(WB,  Wcat + DDIM * DDIM,   n4_w);
    cvt4<<<n4_w / 256, 256, 0, stream>>>(Wdt, Wcat + 2 * DDIM * DDIM, n4_w);

    gemm_fused<<<dim3(128, 24), 256, 0, stream>>>(Fb, Wcat, bA, bB, bdt,
                                                  wsA, vseq, xseq);

    scan_pass1<<<1024, 256, 0, stream>>>(wsA, vseq, xseq, summ);
    scan_pass2<<<16, 256, 0, stream>>>(summ, carry);
    scan_pass3<<<1024, 256, 0, stream>>>(wsA, vseq, xseq, carry);
}